// Round 1
// baseline (287.090 us; speedup 1.0000x reference)
//
#include <hip/hip_runtime.h>
#include <cstdint>
#include <cstddef>

#define NN 4096
#define FDIM 256
#define NBLK 256

typedef __attribute__((ext_vector_type(4))) float fx4;
typedef __attribute__((ext_vector_type(8))) short s8v;

// Monotonic grid-barrier state: zeroed at module load, never reset.
// Invariant after any complete launch: g_cnt == g_flag * NBLK.
__device__ int g_cnt;
__device__ int g_flag;

__device__ inline uint16_t f2bf(float f) {
    union { float f; uint32_t u; } v; v.f = f;
    const uint32_t u = v.u;
    return (uint16_t)((u + 0x7FFFu + ((u >> 16) & 1u)) >> 16);
}

struct ShA { float xs[2][64 * 68]; float wt[2][64 * 68]; };              // 69632 B
struct ShP { float E1s[NN]; float E2s[NN]; float red1[8]; float red2[8];
             int wtot[8]; int base_s; };                                 // ~32.9 KB
struct ShF { uint16_t As[2][64 * 72]; uint16_t Gs[2][256 * 64]; };       // 83968 B
union ShMem { ShA a; ShP p; ShF f; float cex[4][64 * 68]; };             // 83968 B max

// Device-scope sense-free grid barrier (monotonic epochs; 256 blocks, 1/CU).
__device__ __forceinline__ void gbar(int target) {
    __syncthreads();
    if (threadIdx.x == 0) {
        __threadfence();
        const int prev = __hip_atomic_fetch_add(&g_cnt, 1, __ATOMIC_ACQ_REL,
                                                __HIP_MEMORY_SCOPE_AGENT);
        if (prev == target * NBLK - 1) {
            __hip_atomic_store(&g_flag, target, __ATOMIC_RELEASE,
                               __HIP_MEMORY_SCOPE_AGENT);
        } else {
            while (__hip_atomic_load(&g_flag, __ATOMIC_ACQUIRE,
                                     __HIP_MEMORY_SCOPE_AGENT) < target)
                __builtin_amdgcn_s_sleep(2);
        }
        __threadfence();
    }
    __syncthreads();
}

__global__ __launch_bounds__(512, 2) void gat_all(
        const float* __restrict__ x, const int* __restrict__ adj,
        const float* __restrict__ W, const float* __restrict__ bias,
        const float* __restrict__ att_w, uint16_t* __restrict__ gt,
        float* __restrict__ a1p, float* __restrict__ a2p,
        float* __restrict__ E1, float* __restrict__ E2,
        float* __restrict__ wraw, float* __restrict__ Sg,
        uint16_t* __restrict__ part, float* __restrict__ out) {
    __shared__ __align__(16) ShMem sh;
    __shared__ int sh_base;
    const int t = threadIdx.x;
    const int b = blockIdx.x;
    if (t == 0)
        sh_base = __hip_atomic_load(&g_flag, __ATOMIC_RELAXED, __HIP_MEMORY_SCOPE_AGENT);
    __syncthreads();
    const int ep0 = sh_base;

    // ============ Phase A: h = x@W.T + b (fp32, 64x64 tile, K-split) ============
    // epilogue: a1/a2 chunk partials + gt = bf16(h) transposed cb-swizzled write.
    // h never hits global memory.
    {
        const int bi = b & 63, bf = b >> 6;
        const int t256 = t & 255;
        const int kh = t >> 8;
        const int tx = t256 & 15, ty = t256 >> 4;
        float acc[4][4] = {};
        float rx[8], rw[8];
        #pragma unroll
        for (int u = 0; u < 8; ++u) {
            const int e = t + 512 * u, r = e >> 6, c = e & 63;
            rx[u] = x[(size_t)(bi * 64 + r) * 256 + c];
            rw[u] = W[(size_t)(bf * 64 + r) * 256 + c];
        }
        for (int p = 0; p < 4; ++p) {
            float* xb = sh.a.xs[p & 1];
            float* wb = sh.a.wt[p & 1];
            #pragma unroll
            for (int u = 0; u < 8; ++u) {
                const int e = t + 512 * u, r = e >> 6, c = e & 63;
                const int sw = 8 * ((c & 7) ^ ((c >> 3) & 7));
                xb[c * 68 + (r ^ sw)] = rx[u];
                wb[c * 68 + (r ^ sw)] = rw[u];
            }
            __syncthreads();
            if (p < 3) {
                const int kc = (p + 1) * 64;
                #pragma unroll
                for (int u = 0; u < 8; ++u) {
                    const int e = t + 512 * u, r = e >> 6, c = e & 63;
                    rx[u] = x[(size_t)(bi * 64 + r) * 256 + kc + c];
                    rw[u] = W[(size_t)(bf * 64 + r) * 256 + kc + c];
                }
            }
            #pragma unroll 8
            for (int k = 0; k < 32; ++k) {
                const int kk = kh * 32 + k;
                const int sw = 8 * ((kk & 7) ^ ((kk >> 3) & 7));
                const fx4 av = *(const fx4*)(xb + kk * 68 + ((ty * 4) ^ sw));
                const fx4 bv = *(const fx4*)(wb + kk * 68 + ((tx * 4) ^ sw));
                #pragma unroll
                for (int u = 0; u < 4; ++u)
                    #pragma unroll
                    for (int v = 0; v < 4; ++v)
                        acc[u][v] += av[u] * bv[v];
            }
        }
        __syncthreads();
        float* cbuf = sh.a.xs[0];
        if (kh == 1) {
            #pragma unroll
            for (int u = 0; u < 4; ++u)
                *(fx4*)(cbuf + t256 * 16 + u * 4) = *(const fx4*)(&acc[u][0]);
        }
        __syncthreads();
        if (kh == 0) {
            float* tileT = sh.a.wt[0];     // free after compute: [f_local][j_local] pad68
            #pragma unroll
            for (int u = 0; u < 4; ++u) {
                const fx4 o = *(const fx4*)(cbuf + t256 * 16 + u * 4);
                #pragma unroll
                for (int v = 0; v < 4; ++v) acc[u][v] += o[v];
            }
            const fx4 bv = *(const fx4*)(bias + bf * 64 + tx * 4);
            const fx4 w1v = *(const fx4*)(att_w + bf * 64 + tx * 4);
            const fx4 w2v = *(const fx4*)(att_w + 256 + bf * 64 + tx * 4);
            #pragma unroll
            for (int u = 0; u < 4; ++u) {
                const int i = bi * 64 + ty * 4 + u;
                fx4 r;
                float s1 = 0.f, s2 = 0.f;
                #pragma unroll
                for (int v = 0; v < 4; ++v) {
                    r[v] = acc[u][v] + bv[v];
                    s1 += r[v] * w1v[v];
                    s2 += r[v] * w2v[v];
                }
                #pragma unroll
                for (int v = 0; v < 4; ++v)
                    tileT[(tx * 4 + v) * 68 + ty * 4 + u] = r[v];
                #pragma unroll
                for (int d = 8; d > 0; d >>= 1) {
                    s1 += __shfl_down(s1, d, 16);
                    s2 += __shfl_down(s2, d, 16);
                }
                if (tx == 0) {
                    a1p[bf * NN + i] = s1;
                    a2p[bf * NN + i] = s2;
                }
            }
        }
        __syncthreads();
        {   // gt store stage: all 512 threads, 64 f-rows x 8 cb each
            const float* tileT = sh.a.wt[0];
            const int fl = t >> 3, cb = t & 7;
            const int pcb = cb ^ (fl & 7);
            s8v v;
            #pragma unroll
            for (int lo = 0; lo < 8; ++lo)
                v[lo] = (short)f2bf(tileT[fl * 68 + cb * 8 + lo]);
            *(s8v*)(gt + (size_t)(bf * 64 + fl) * NN + bi * 64 + pcb * 8) = v;
        }
    }

    gbar(ep0 + 1);

    // ---- fused-phase prefetch issued early (depends only on adj / phase A) ----
    const int ib = b & 63, ks = b >> 6;                 // splitk = 4
    const int i0 = ib * 64, k0f = ks * 1024;
    const int wv = t >> 6, lane = t & 63;
    const int ar = t >> 4, ac4 = (t & 15) * 4;
    const int fr = lane >> 3, cbd = lane & 7;
    int4 ra[2];
    #pragma unroll
    for (int p = 0; p < 2; ++p)
        ra[p] = *(const int4*)(adj + (size_t)(i0 + p * 32 + ar) * NN + k0f + ac4);

    // ============ Phase P: softmax prep (block 0 only; others spin) ============
    if (b == 0) {
        const int wvi = t >> 6;
        fx4 v1a = {0.f,0.f,0.f,0.f}, v1b = {0.f,0.f,0.f,0.f};
        fx4 v2a = {0.f,0.f,0.f,0.f}, v2b = {0.f,0.f,0.f,0.f};
        #pragma unroll
        for (int bf = 0; bf < 4; ++bf) {
            v1a += *(const fx4*)(a1p + bf * NN + t * 8);
            v1b += *(const fx4*)(a1p + bf * NN + t * 8 + 4);
            v2a += *(const fx4*)(a2p + bf * NN + t * 8);
            v2b += *(const fx4*)(a2p + bf * NN + t * 8 + 4);
        }
        float m1 = fmaxf(fmaxf(fmaxf(v1a[0], v1a[1]), fmaxf(v1a[2], v1a[3])),
                         fmaxf(fmaxf(v1b[0], v1b[1]), fmaxf(v1b[2], v1b[3])));
        float m2 = fmaxf(fmaxf(fmaxf(v2a[0], v2a[1]), fmaxf(v2a[2], v2a[3])),
                         fmaxf(fmaxf(v2b[0], v2b[1]), fmaxf(v2b[2], v2b[3])));
        #pragma unroll
        for (int d = 32; d > 0; d >>= 1) {
            m1 = fmaxf(m1, __shfl_down(m1, d));
            m2 = fmaxf(m2, __shfl_down(m2, d));
        }
        if (lane == 0) { sh.p.red1[wvi] = m1; sh.p.red2[wvi] = m2; }
        __syncthreads();
        if (t == 0) {
            float mm1 = -1e30f, mm2 = -1e30f;
            for (int k = 0; k < 8; ++k) {
                mm1 = fmaxf(mm1, sh.p.red1[k]);
                mm2 = fmaxf(mm2, sh.p.red2[k]);
            }
            sh.p.red1[0] = mm1; sh.p.red2[0] = mm2;
            *Sg = 0.f;
            sh.p.base_s = 0;
        }
        __syncthreads();
        const float M1 = sh.p.red1[0], M2 = sh.p.red2[0];
        fx4 e1a, e1b, e2a, e2b;
        #pragma unroll
        for (int j = 0; j < 4; ++j) {
            e1a[j] = expf(v1a[j] - M1); e1b[j] = expf(v1b[j] - M1);
            e2a[j] = expf(v2a[j] - M2); e2b[j] = expf(v2b[j] - M2);
        }
        *(fx4*)(sh.p.E1s + t * 8) = e1a; *(fx4*)(sh.p.E1s + t * 8 + 4) = e1b;
        *(fx4*)(sh.p.E2s + t * 8) = e2a; *(fx4*)(sh.p.E2s + t * 8 + 4) = e2b;
        *(fx4*)(E1 + t * 8) = e1a;       *(fx4*)(E1 + t * 8 + 4) = e1b;
        *(fx4*)(E2 + t * 8) = e2a;       *(fx4*)(E2 + t * 8 + 4) = e2b;
        const fx4 z4 = {0.f, 0.f, 0.f, 0.f};
        *(fx4*)(wraw + t * 8) = z4;      *(fx4*)(wraw + t * 8 + 4) = z4;
        __syncthreads();
        for (int row = 0; row < NN; ++row) {
            const int base = sh.p.base_s;
            if (base >= NN) break;
            const int4 a0 = ((const int4*)(adj + (size_t)row * NN))[t * 2];
            const int4 a1v = ((const int4*)(adj + (size_t)row * NN))[t * 2 + 1];
            const int vj[8] = {a0.x, a0.y, a0.z, a0.w, a1v.x, a1v.y, a1v.z, a1v.w};
            int cnt = 0;
            #pragma unroll
            for (int j = 0; j < 8; ++j) cnt += (vj[j] == 1);
            int inc = cnt;
            #pragma unroll
            for (int d = 1; d < 64; d <<= 1) {
                const int y = __shfl_up(inc, d);
                if (lane >= d) inc += y;
            }
            if (lane == 63) sh.p.wtot[wvi] = inc;
            __syncthreads();
            int wbase = 0, total = 0;
            #pragma unroll
            for (int w = 0; w < 8; ++w) {
                const int xw = sh.p.wtot[w];
                total += xw;
                wbase += (w < wvi) ? xw : 0;
            }
            if (t == 0) sh.p.base_s = base + total;
            int r = base + wbase + inc - cnt;
            if (cnt && r < NN) {
                const float e1 = sh.p.E1s[row];
                #pragma unroll
                for (int j = 0; j < 8; ++j) {
                    if (vj[j] == 1) {
                        if (r < NN) wraw[r] = e1 * sh.p.E2s[t * 8 + j];
                        ++r;
                    }
                }
            }
            __syncthreads();
        }
    }

    // Gs[0] DMA (block 0 issues post-prep so the union aliasing is safe)
    #pragma unroll
    for (int p = 0; p < 4; ++p) {
        const uint16_t* gp = gt + (size_t)(wv * 32 + p * 8 + fr) * NN + k0f + cbd * 8;
        __builtin_amdgcn_global_load_lds(
            (const __attribute__((address_space(1))) uint32_t*)gp,
            (__attribute__((address_space(3))) uint32_t*)(&sh.f.Gs[0][(wv * 32 + p * 8) * 64]),
            16, 0, 0);
    }

    gbar(ep0 + 2);

    // ============ Phase F: part = (adj*bf16(wraw)) @ bf16(h)^T + exact S ========
    // 8 waves: kh-split (wv>>2) x f-quad (wv&3); As+Gs double-buffered, DMA for
    // step t+1 issued before step t's MFMA so the barrier vmcnt drain is cheap.
    {
        const int q = lane >> 4, m16 = lane & 15;
        const int khw = wv >> 2, fquad = wv & 3;
        fx4 acc[4][4];
        #pragma unroll
        for (int a2 = 0; a2 < 4; ++a2)
            #pragma unroll
            for (int b2 = 0; b2 < 4; ++b2) acc[a2][b2] = (fx4){0.f, 0.f, 0.f, 0.f};
        float sS = 0.f;
        const float e1r0 = E1[i0 + ar];
        const float e1r1 = E1[i0 + 32 + ar];
        fx4 rw4 = *(const fx4*)(wraw + k0f + ac4);
        fx4 re2 = *(const fx4*)(E2 + k0f + ac4);
        {   // As[0] + S contribution of step 0 (from prefetched ra)
            const uint16_t wb0 = f2bf(rw4[0]), wb1 = f2bf(rw4[1]);
            const uint16_t wb2 = f2bf(rw4[2]), wb3 = f2bf(rw4[3]);
            #pragma unroll
            for (int p = 0; p < 2; ++p) {
                uint2 wo;
                wo.x = (ra[p].x == 1 ? (uint32_t)wb0 : 0u) |
                       ((ra[p].y == 1 ? (uint32_t)wb1 : 0u) << 16);
                wo.y = (ra[p].z == 1 ? (uint32_t)wb2 : 0u) |
                       ((ra[p].w == 1 ? (uint32_t)wb3 : 0u) << 16);
                *(uint2*)(&sh.f.As[0][(p * 32 + ar) * 72 + ac4]) = wo;
            }
            sS += e1r0 * ((ra[0].x == 1 ? re2[0] : 0.f) + (ra[0].y == 1 ? re2[1] : 0.f) +
                          (ra[0].z == 1 ? re2[2] : 0.f) + (ra[0].w == 1 ? re2[3] : 0.f));
            sS += e1r1 * ((ra[1].x == 1 ? re2[0] : 0.f) + (ra[1].y == 1 ? re2[1] : 0.f) +
                          (ra[1].z == 1 ? re2[2] : 0.f) + (ra[1].w == 1 ? re2[3] : 0.f));
        }
        __syncthreads();
        const int pcb = ((khw << 2) | q) ^ (m16 & 7);
        for (int stp = 0; stp < 16; ++stp) {
            const int cur = stp & 1, nxt = cur ^ 1;
            const int kk = k0f + stp * 64;
            if (stp < 15) {
                #pragma unroll
                for (int p = 0; p < 4; ++p) {
                    const uint16_t* gp =
                        gt + (size_t)(wv * 32 + p * 8 + fr) * NN + kk + 64 + cbd * 8;
                    __builtin_amdgcn_global_load_lds(
                        (const __attribute__((address_space(1))) uint32_t*)gp,
                        (__attribute__((address_space(3))) uint32_t*)(&sh.f.Gs[nxt][(wv * 32 + p * 8) * 64]),
                        16, 0, 0);
                }
                #pragma unroll
                for (int p = 0; p < 2; ++p)
                    ra[p] = *(const int4*)(adj + (size_t)(i0 + p * 32 + ar) * NN +
                                           kk + 64 + ac4);
                rw4 = *(const fx4*)(wraw + kk + 64 + ac4);
                re2 = *(const fx4*)(E2 + kk + 64 + ac4);
            }
            s8v afr[4];
            #pragma unroll
            for (int it = 0; it < 4; ++it)
                afr[it] = *(const s8v*)(&sh.f.As[cur][(it * 16 + m16) * 72 + khw * 32 + q * 8]);
            #pragma unroll
            for (int ft = 0; ft < 4; ++ft) {
                const int row = fquad * 64 + ft * 16 + m16;
                const s8v bfr = *(const s8v*)(&sh.f.Gs[cur][row * 64 + pcb * 8]);
                #pragma unroll
                for (int it = 0; it < 4; ++it)
                    acc[it][ft] = __builtin_amdgcn_mfma_f32_16x16x32_bf16(
                        afr[it], bfr, acc[it][ft], 0, 0, 0);
            }
            if (stp < 15) {   // stage next As + S partial from just-prefetched regs
                const uint16_t wb0 = f2bf(rw4[0]), wb1 = f2bf(rw4[1]);
                const uint16_t wb2 = f2bf(rw4[2]), wb3 = f2bf(rw4[3]);
                #pragma unroll
                for (int p = 0; p < 2; ++p) {
                    uint2 wo;
                    wo.x = (ra[p].x == 1 ? (uint32_t)wb0 : 0u) |
                           ((ra[p].y == 1 ? (uint32_t)wb1 : 0u) << 16);
                    wo.y = (ra[p].z == 1 ? (uint32_t)wb2 : 0u) |
                           ((ra[p].w == 1 ? (uint32_t)wb3 : 0u) << 16);
                    *(uint2*)(&sh.f.As[nxt][(p * 32 + ar) * 72 + ac4]) = wo;
                }
                sS += e1r0 * ((ra[0].x == 1 ? re2[0] : 0.f) + (ra[0].y == 1 ? re2[1] : 0.f) +
                              (ra[0].z == 1 ? re2[2] : 0.f) + (ra[0].w == 1 ? re2[3] : 0.f));
                sS += e1r1 * ((ra[1].x == 1 ? re2[0] : 0.f) + (ra[1].y == 1 ? re2[1] : 0.f) +
                              (ra[1].z == 1 ? re2[2] : 0.f) + (ra[1].w == 1 ? re2[3] : 0.f));
            }
            __syncthreads();
        }
        #pragma unroll
        for (int d = 32; d > 0; d >>= 1) sS += __shfl_down(sS, d);
        if (lane == 0) atomicAdd(Sg, sS);
        // combine kh halves via LDS (cex aliases As/Gs: dead after last barrier)
        if (wv >= 4) {
            float* cx = &sh.cex[fquad][0] + lane * 68;
            #pragma unroll
            for (int it = 0; it < 4; ++it)
                #pragma unroll
                for (int ft = 0; ft < 4; ++ft)
                    *(fx4*)(cx + it * 16 + ft * 4) = acc[it][ft];
        }
        __syncthreads();
        if (wv < 4) {
            const float* cx = &sh.cex[fquad][0] + lane * 68;
            uint16_t* dst = part + (size_t)ks * NN * FDIM;
            #pragma unroll
            for (int it = 0; it < 4; ++it)
                #pragma unroll
                for (int ft = 0; ft < 4; ++ft) {
                    const fx4 o = *(const fx4*)(cx + it * 16 + ft * 4);
                    const int f = fquad * 64 + ft * 16 + m16;
                    #pragma unroll
                    for (int r = 0; r < 4; ++r)
                        dst[(size_t)(i0 + it * 16 + q * 4 + r) * FDIM + f] =
                            f2bf(acc[it][ft][r] + o[r]);
                }
        }
    }

    gbar(ep0 + 3);

    // ============ Phase O: out = relu(sum_k part_k) / S ========================
    {
        const size_t idx = ((size_t)b * 512 + t) * 8;
        const float inv = 1.0f / (*Sg);
        float s[8] = {};
        #pragma unroll
        for (int k = 0; k < 4; ++k) {
            const s8v v = *(const s8v*)(part + (size_t)k * NN * FDIM + idx);
            #pragma unroll
            for (int j = 0; j < 8; ++j) {
                union { uint32_t u; float f; } cv;
                cv.u = ((uint32_t)(uint16_t)v[j]) << 16;
                s[j] += cv.f;
            }
        }
        fx4 r0, r1;
        #pragma unroll
        for (int j = 0; j < 4; ++j) {
            r0[j] = fmaxf(s[j], 0.f) * inv;
            r1[j] = fmaxf(s[4 + j], 0.f) * inv;
        }
        *(fx4*)(out + idx) = r0;
        *(fx4*)(out + idx + 4) = r1;
    }
}

extern "C" void kernel_launch(void* const* d_in, const int* in_sizes, int n_in,
                              void* d_out, int out_size, void* d_ws, size_t ws_size,
                              hipStream_t stream) {
    const float* x     = (const float*)d_in[0];
    const int*   adj   = (const int*)d_in[1];
    const float* W     = (const float*)d_in[2];
    const float* bias  = (const float*)d_in[3];
    const float* att_w = (const float*)d_in[4];
    // att_b (d_in[5]) cancels exactly in the softmax — unused.
    float* out = (float*)d_out;
    char* ws = (char*)d_ws;
    uint16_t* gt   = (uint16_t*)(ws + 0);            // 2 MB: bf16(h) transposed
    float*    a1p  = (float*)(ws + 2097152);         // 64 KB
    float*    a2p  = (float*)(ws + 2162688);         // 64 KB
    float*    E1   = (float*)(ws + 2228224);         // 16 KB
    float*    E2   = (float*)(ws + 2244608);         // 16 KB
    float*    wraw = (float*)(ws + 2260992);         // 16 KB
    float*    Sg   = (float*)(ws + 2277376);         // 256 B
    uint16_t* part = (uint16_t*)(ws + 2277632);      // 4 x 2 MB bf16 split-K partials
    (void)in_sizes; (void)n_in; (void)out_size; (void)ws_size;

    gat_all<<<dim3(NBLK), 512, 0, stream>>>(x, adj, W, bias, att_w, gt, a1p, a2p,
                                            E1, E2, wraw, Sg, part, out);
}

// Round 2
// 192.406 us; speedup vs baseline: 1.4921x; 1.4921x over previous
//
#include <hip/hip_runtime.h>
#include <cstdint>
#include <cstddef>

#define NN 4096
#define FDIM 256
#define NBLK 256

typedef __attribute__((ext_vector_type(4))) float fx4;
typedef __attribute__((ext_vector_type(8))) short s8v;

// Monotonic grid-barrier state: zeroed at module load, never reset.
// Invariant after any complete launch: g_cnt == g_flag * NBLK.
__device__ int g_cnt;
__device__ int g_flag;

__device__ inline uint16_t f2bf(float f) {
    union { float f; uint32_t u; } v; v.f = f;
    const uint32_t u = v.u;
    return (uint16_t)((u + 0x7FFFu + ((u >> 16) & 1u)) >> 16);
}

struct ShA { float xs[2][64 * 68]; float wt[2][64 * 68]; };              // 69632 B
struct ShP { float E1s[NN]; float E2s[NN]; float red1[8]; float red2[8];
             int wtot[8]; int base_s; };                                 // ~32.9 KB
struct ShF { uint16_t As[2][64 * 72]; uint16_t Gs[2][256 * 64]; };       // 83968 B
union ShMem { ShA a; ShP p; ShF f; float cex[4][64 * 68]; };             // 83968 B max

// Device-scope grid barrier, cooperative-groups style:
// - arrival: one ACQ_REL fetch_add per block (release this block's writes;
//   the last block's RMW acquires the whole chain)
// - last block: RELEASE store of the epoch flag
// - waiters: RELAXED spin (coherent load, NO per-poll cache invalidate) +
//   one ACQUIRE fence after the flag is observed.
// Round-1 version spun on ACQUIRE loads: each poll flash-invalidated the
// XCD's L1+L2 -> 255 pollers destroyed all cache locality (212 us, all idle).
__device__ __forceinline__ void gbar(int target) {
    __syncthreads();
    if (threadIdx.x == 0) {
        const int prev = __hip_atomic_fetch_add(&g_cnt, 1, __ATOMIC_ACQ_REL,
                                                __HIP_MEMORY_SCOPE_AGENT);
        if (prev == target * NBLK - 1) {
            __hip_atomic_store(&g_flag, target, __ATOMIC_RELEASE,
                               __HIP_MEMORY_SCOPE_AGENT);
        } else {
            while (__hip_atomic_load(&g_flag, __ATOMIC_RELAXED,
                                     __HIP_MEMORY_SCOPE_AGENT) < target)
                __builtin_amdgcn_s_sleep(8);
            __builtin_amdgcn_fence(__ATOMIC_ACQUIRE, "agent");
        }
    }
    __syncthreads();
}

__global__ __launch_bounds__(512, 2) void gat_all(
        const float* __restrict__ x, const int* __restrict__ adj,
        const float* __restrict__ W, const float* __restrict__ bias,
        const float* __restrict__ att_w, uint16_t* __restrict__ gt,
        float* __restrict__ a1p, float* __restrict__ a2p,
        float* __restrict__ E1, float* __restrict__ E2,
        float* __restrict__ wraw, float* __restrict__ Sg,
        uint16_t* __restrict__ part, float* __restrict__ out) {
    __shared__ __align__(16) ShMem sh;
    __shared__ int sh_base;
    __shared__ float sgred[8];
    const int t = threadIdx.x;
    const int b = blockIdx.x;
    if (t == 0)
        sh_base = __hip_atomic_load(&g_flag, __ATOMIC_RELAXED, __HIP_MEMORY_SCOPE_AGENT);
    __syncthreads();
    const int ep0 = sh_base;

    // ============ Phase A: h = x@W.T + b (fp32, 64x64 tile, K-split) ============
    // epilogue: a1/a2 chunk partials + gt = bf16(h) transposed cb-swizzled write.
    // h never hits global memory.
    {
        const int bi = b & 63, bf = b >> 6;
        const int t256 = t & 255;
        const int kh = t >> 8;
        const int tx = t256 & 15, ty = t256 >> 4;
        float acc[4][4] = {};
        float rx[8], rw[8];
        #pragma unroll
        for (int u = 0; u < 8; ++u) {
            const int e = t + 512 * u, r = e >> 6, c = e & 63;
            rx[u] = x[(size_t)(bi * 64 + r) * 256 + c];
            rw[u] = W[(size_t)(bf * 64 + r) * 256 + c];
        }
        for (int p = 0; p < 4; ++p) {
            float* xb = sh.a.xs[p & 1];
            float* wb = sh.a.wt[p & 1];
            #pragma unroll
            for (int u = 0; u < 8; ++u) {
                const int e = t + 512 * u, r = e >> 6, c = e & 63;
                const int sw = 8 * ((c & 7) ^ ((c >> 3) & 7));
                xb[c * 68 + (r ^ sw)] = rx[u];
                wb[c * 68 + (r ^ sw)] = rw[u];
            }
            __syncthreads();
            if (p < 3) {
                const int kc = (p + 1) * 64;
                #pragma unroll
                for (int u = 0; u < 8; ++u) {
                    const int e = t + 512 * u, r = e >> 6, c = e & 63;
                    rx[u] = x[(size_t)(bi * 64 + r) * 256 + kc + c];
                    rw[u] = W[(size_t)(bf * 64 + r) * 256 + kc + c];
                }
            }
            #pragma unroll 8
            for (int k = 0; k < 32; ++k) {
                const int kk = kh * 32 + k;
                const int sw = 8 * ((kk & 7) ^ ((kk >> 3) & 7));
                const fx4 av = *(const fx4*)(xb + kk * 68 + ((ty * 4) ^ sw));
                const fx4 bv = *(const fx4*)(wb + kk * 68 + ((tx * 4) ^ sw));
                #pragma unroll
                for (int u = 0; u < 4; ++u)
                    #pragma unroll
                    for (int v = 0; v < 4; ++v)
                        acc[u][v] += av[u] * bv[v];
            }
        }
        __syncthreads();
        float* cbuf = sh.a.xs[0];
        if (kh == 1) {
            #pragma unroll
            for (int u = 0; u < 4; ++u)
                *(fx4*)(cbuf + t256 * 16 + u * 4) = *(const fx4*)(&acc[u][0]);
        }
        __syncthreads();
        if (kh == 0) {
            float* tileT = sh.a.wt[0];     // free after compute: [f_local][j_local] pad68
            #pragma unroll
            for (int u = 0; u < 4; ++u) {
                const fx4 o = *(const fx4*)(cbuf + t256 * 16 + u * 4);
                #pragma unroll
                for (int v = 0; v < 4; ++v) acc[u][v] += o[v];
            }
            const fx4 bv = *(const fx4*)(bias + bf * 64 + tx * 4);
            const fx4 w1v = *(const fx4*)(att_w + bf * 64 + tx * 4);
            const fx4 w2v = *(const fx4*)(att_w + 256 + bf * 64 + tx * 4);
            #pragma unroll
            for (int u = 0; u < 4; ++u) {
                const int i = bi * 64 + ty * 4 + u;
                fx4 r;
                float s1 = 0.f, s2 = 0.f;
                #pragma unroll
                for (int v = 0; v < 4; ++v) {
                    r[v] = acc[u][v] + bv[v];
                    s1 += r[v] * w1v[v];
                    s2 += r[v] * w2v[v];
                }
                #pragma unroll
                for (int v = 0; v < 4; ++v)
                    tileT[(tx * 4 + v) * 68 + ty * 4 + u] = r[v];
                #pragma unroll
                for (int d = 8; d > 0; d >>= 1) {
                    s1 += __shfl_down(s1, d, 16);
                    s2 += __shfl_down(s2, d, 16);
                }
                if (tx == 0) {
                    a1p[bf * NN + i] = s1;
                    a2p[bf * NN + i] = s2;
                }
            }
        }
        __syncthreads();
        {   // gt store stage: all 512 threads, 64 f-rows x 8 cb each
            const float* tileT = sh.a.wt[0];
            const int fl = t >> 3, cb = t & 7;
            const int pcb = cb ^ (fl & 7);
            s8v v;
            #pragma unroll
            for (int lo = 0; lo < 8; ++lo)
                v[lo] = (short)f2bf(tileT[fl * 68 + cb * 8 + lo]);
            *(s8v*)(gt + (size_t)(bf * 64 + fl) * NN + bi * 64 + pcb * 8) = v;
        }
    }

    gbar(ep0 + 1);

    // ---- fused-phase prefetch issued early (depends only on adj / phase A) ----
    const int ib = b & 63, ks = b >> 6;                 // splitk = 4
    const int i0 = ib * 64, k0f = ks * 1024;
    const int wv = t >> 6, lane = t & 63;
    const int ar = t >> 4, ac4 = (t & 15) * 4;
    const int fr = lane >> 3, cbd = lane & 7;
    int4 ra[2];
    #pragma unroll
    for (int p = 0; p < 2; ++p)
        ra[p] = *(const int4*)(adj + (size_t)(i0 + p * 32 + ar) * NN + k0f + ac4);

    // ============ Phase P: softmax prep (block 0 only; others spin) ============
    if (b == 0) {
        const int wvi = t >> 6;
        fx4 v1a = {0.f,0.f,0.f,0.f}, v1b = {0.f,0.f,0.f,0.f};
        fx4 v2a = {0.f,0.f,0.f,0.f}, v2b = {0.f,0.f,0.f,0.f};
        #pragma unroll
        for (int bf = 0; bf < 4; ++bf) {
            v1a += *(const fx4*)(a1p + bf * NN + t * 8);
            v1b += *(const fx4*)(a1p + bf * NN + t * 8 + 4);
            v2a += *(const fx4*)(a2p + bf * NN + t * 8);
            v2b += *(const fx4*)(a2p + bf * NN + t * 8 + 4);
        }
        float m1 = fmaxf(fmaxf(fmaxf(v1a[0], v1a[1]), fmaxf(v1a[2], v1a[3])),
                         fmaxf(fmaxf(v1b[0], v1b[1]), fmaxf(v1b[2], v1b[3])));
        float m2 = fmaxf(fmaxf(fmaxf(v2a[0], v2a[1]), fmaxf(v2a[2], v2a[3])),
                         fmaxf(fmaxf(v2b[0], v2b[1]), fmaxf(v2b[2], v2b[3])));
        #pragma unroll
        for (int d = 32; d > 0; d >>= 1) {
            m1 = fmaxf(m1, __shfl_down(m1, d));
            m2 = fmaxf(m2, __shfl_down(m2, d));
        }
        if (lane == 0) { sh.p.red1[wvi] = m1; sh.p.red2[wvi] = m2; }
        __syncthreads();
        if (t == 0) {
            float mm1 = -1e30f, mm2 = -1e30f;
            for (int k = 0; k < 8; ++k) {
                mm1 = fmaxf(mm1, sh.p.red1[k]);
                mm2 = fmaxf(mm2, sh.p.red2[k]);
            }
            sh.p.red1[0] = mm1; sh.p.red2[0] = mm2;
            *Sg = 0.f;
            sh.p.base_s = 0;
        }
        __syncthreads();
        const float M1 = sh.p.red1[0], M2 = sh.p.red2[0];
        fx4 e1a, e1b, e2a, e2b;
        #pragma unroll
        for (int j = 0; j < 4; ++j) {
            e1a[j] = expf(v1a[j] - M1); e1b[j] = expf(v1b[j] - M1);
            e2a[j] = expf(v2a[j] - M2); e2b[j] = expf(v2b[j] - M2);
        }
        *(fx4*)(sh.p.E1s + t * 8) = e1a; *(fx4*)(sh.p.E1s + t * 8 + 4) = e1b;
        *(fx4*)(sh.p.E2s + t * 8) = e2a; *(fx4*)(sh.p.E2s + t * 8 + 4) = e2b;
        *(fx4*)(E1 + t * 8) = e1a;       *(fx4*)(E1 + t * 8 + 4) = e1b;
        *(fx4*)(E2 + t * 8) = e2a;       *(fx4*)(E2 + t * 8 + 4) = e2b;
        const fx4 z4 = {0.f, 0.f, 0.f, 0.f};
        *(fx4*)(wraw + t * 8) = z4;      *(fx4*)(wraw + t * 8 + 4) = z4;
        __syncthreads();
        for (int row = 0; row < NN; ++row) {
            const int base = sh.p.base_s;
            if (base >= NN) break;
            const int4 a0 = ((const int4*)(adj + (size_t)row * NN))[t * 2];
            const int4 a1v = ((const int4*)(adj + (size_t)row * NN))[t * 2 + 1];
            const int vj[8] = {a0.x, a0.y, a0.z, a0.w, a1v.x, a1v.y, a1v.z, a1v.w};
            int cnt = 0;
            #pragma unroll
            for (int j = 0; j < 8; ++j) cnt += (vj[j] == 1);
            int inc = cnt;
            #pragma unroll
            for (int d = 1; d < 64; d <<= 1) {
                const int y = __shfl_up(inc, d);
                if (lane >= d) inc += y;
            }
            if (lane == 63) sh.p.wtot[wvi] = inc;
            __syncthreads();
            int wbase = 0, total = 0;
            #pragma unroll
            for (int w = 0; w < 8; ++w) {
                const int xw = sh.p.wtot[w];
                total += xw;
                wbase += (w < wvi) ? xw : 0;
            }
            if (t == 0) sh.p.base_s = base + total;
            int r = base + wbase + inc - cnt;
            if (cnt && r < NN) {
                const float e1 = sh.p.E1s[row];
                #pragma unroll
                for (int j = 0; j < 8; ++j) {
                    if (vj[j] == 1) {
                        if (r < NN) wraw[r] = e1 * sh.p.E2s[t * 8 + j];
                        ++r;
                    }
                }
            }
            __syncthreads();
        }
    }

    // Gs[0] DMA (block 0 issues post-prep so the union aliasing is safe)
    #pragma unroll
    for (int p = 0; p < 4; ++p) {
        const uint16_t* gp = gt + (size_t)(wv * 32 + p * 8 + fr) * NN + k0f + cbd * 8;
        __builtin_amdgcn_global_load_lds(
            (const __attribute__((address_space(1))) uint32_t*)gp,
            (__attribute__((address_space(3))) uint32_t*)(&sh.f.Gs[0][(wv * 32 + p * 8) * 64]),
            16, 0, 0);
    }

    gbar(ep0 + 2);

    // ============ Phase F: part = (adj*bf16(wraw)) @ bf16(h)^T + exact S ========
    // 8 waves: kh-split (wv>>2) x f-quad (wv&3); As+Gs double-buffered, DMA for
    // step t+1 issued before step t's MFMA so the barrier vmcnt drain is cheap.
    {
        const int q = lane >> 4, m16 = lane & 15;
        const int khw = wv >> 2, fquad = wv & 3;
        fx4 acc[4][4];
        #pragma unroll
        for (int a2 = 0; a2 < 4; ++a2)
            #pragma unroll
            for (int b2 = 0; b2 < 4; ++b2) acc[a2][b2] = (fx4){0.f, 0.f, 0.f, 0.f};
        float sS = 0.f;
        const float e1r0 = E1[i0 + ar];
        const float e1r1 = E1[i0 + 32 + ar];
        fx4 rw4 = *(const fx4*)(wraw + k0f + ac4);
        fx4 re2 = *(const fx4*)(E2 + k0f + ac4);
        {   // As[0] + S contribution of step 0 (from prefetched ra)
            const uint16_t wb0 = f2bf(rw4[0]), wb1 = f2bf(rw4[1]);
            const uint16_t wb2 = f2bf(rw4[2]), wb3 = f2bf(rw4[3]);
            #pragma unroll
            for (int p = 0; p < 2; ++p) {
                uint2 wo;
                wo.x = (ra[p].x == 1 ? (uint32_t)wb0 : 0u) |
                       ((ra[p].y == 1 ? (uint32_t)wb1 : 0u) << 16);
                wo.y = (ra[p].z == 1 ? (uint32_t)wb2 : 0u) |
                       ((ra[p].w == 1 ? (uint32_t)wb3 : 0u) << 16);
                *(uint2*)(&sh.f.As[0][(p * 32 + ar) * 72 + ac4]) = wo;
            }
            sS += e1r0 * ((ra[0].x == 1 ? re2[0] : 0.f) + (ra[0].y == 1 ? re2[1] : 0.f) +
                          (ra[0].z == 1 ? re2[2] : 0.f) + (ra[0].w == 1 ? re2[3] : 0.f));
            sS += e1r1 * ((ra[1].x == 1 ? re2[0] : 0.f) + (ra[1].y == 1 ? re2[1] : 0.f) +
                          (ra[1].z == 1 ? re2[2] : 0.f) + (ra[1].w == 1 ? re2[3] : 0.f));
        }
        __syncthreads();
        const int pcb = ((khw << 2) | q) ^ (m16 & 7);
        for (int stp = 0; stp < 16; ++stp) {
            const int cur = stp & 1, nxt = cur ^ 1;
            const int kk = k0f + stp * 64;
            if (stp < 15) {
                #pragma unroll
                for (int p = 0; p < 4; ++p) {
                    const uint16_t* gp =
                        gt + (size_t)(wv * 32 + p * 8 + fr) * NN + kk + 64 + cbd * 8;
                    __builtin_amdgcn_global_load_lds(
                        (const __attribute__((address_space(1))) uint32_t*)gp,
                        (__attribute__((address_space(3))) uint32_t*)(&sh.f.Gs[nxt][(wv * 32 + p * 8) * 64]),
                        16, 0, 0);
                }
                #pragma unroll
                for (int p = 0; p < 2; ++p)
                    ra[p] = *(const int4*)(adj + (size_t)(i0 + p * 32 + ar) * NN +
                                           kk + 64 + ac4);
                rw4 = *(const fx4*)(wraw + kk + 64 + ac4);
                re2 = *(const fx4*)(E2 + kk + 64 + ac4);
            }
            s8v afr[4];
            #pragma unroll
            for (int it = 0; it < 4; ++it)
                afr[it] = *(const s8v*)(&sh.f.As[cur][(it * 16 + m16) * 72 + khw * 32 + q * 8]);
            #pragma unroll
            for (int ft = 0; ft < 4; ++ft) {
                const int row = fquad * 64 + ft * 16 + m16;
                const s8v bfr = *(const s8v*)(&sh.f.Gs[cur][row * 64 + pcb * 8]);
                #pragma unroll
                for (int it = 0; it < 4; ++it)
                    acc[it][ft] = __builtin_amdgcn_mfma_f32_16x16x32_bf16(
                        afr[it], bfr, acc[it][ft], 0, 0, 0);
            }
            if (stp < 15) {   // stage next As + S partial from just-prefetched regs
                const uint16_t wb0 = f2bf(rw4[0]), wb1 = f2bf(rw4[1]);
                const uint16_t wb2 = f2bf(rw4[2]), wb3 = f2bf(rw4[3]);
                #pragma unroll
                for (int p = 0; p < 2; ++p) {
                    uint2 wo;
                    wo.x = (ra[p].x == 1 ? (uint32_t)wb0 : 0u) |
                           ((ra[p].y == 1 ? (uint32_t)wb1 : 0u) << 16);
                    wo.y = (ra[p].z == 1 ? (uint32_t)wb2 : 0u) |
                           ((ra[p].w == 1 ? (uint32_t)wb3 : 0u) << 16);
                    *(uint2*)(&sh.f.As[nxt][(p * 32 + ar) * 72 + ac4]) = wo;
                }
                sS += e1r0 * ((ra[0].x == 1 ? re2[0] : 0.f) + (ra[0].y == 1 ? re2[1] : 0.f) +
                              (ra[0].z == 1 ? re2[2] : 0.f) + (ra[0].w == 1 ? re2[3] : 0.f));
                sS += e1r1 * ((ra[1].x == 1 ? re2[0] : 0.f) + (ra[1].y == 1 ? re2[1] : 0.f) +
                              (ra[1].z == 1 ? re2[2] : 0.f) + (ra[1].w == 1 ? re2[3] : 0.f));
            }
            __syncthreads();
        }
        #pragma unroll
        for (int d = 32; d > 0; d >>= 1) sS += __shfl_down(sS, d);
        if (lane == 0) sgred[wv] = sS;
        // combine kh halves via LDS (cex aliases As/Gs: dead after last barrier)
        if (wv >= 4) {
            float* cx = &sh.cex[fquad][0] + lane * 68;
            #pragma unroll
            for (int it = 0; it < 4; ++it)
                #pragma unroll
                for (int ft = 0; ft < 4; ++ft)
                    *(fx4*)(cx + it * 16 + ft * 4) = acc[it][ft];
        }
        __syncthreads();
        if (t == 0) {   // one device atomic per block (was 8)
            float sb = 0.f;
            #pragma unroll
            for (int w = 0; w < 8; ++w) sb += sgred[w];
            atomicAdd(Sg, sb);
        }
        if (wv < 4) {
            const float* cx = &sh.cex[fquad][0] + lane * 68;
            uint16_t* dst = part + (size_t)ks * NN * FDIM;
            #pragma unroll
            for (int it = 0; it < 4; ++it)
                #pragma unroll
                for (int ft = 0; ft < 4; ++ft) {
                    const fx4 o = *(const fx4*)(cx + it * 16 + ft * 4);
                    const int f = fquad * 64 + ft * 16 + m16;
                    #pragma unroll
                    for (int r = 0; r < 4; ++r)
                        dst[(size_t)(i0 + it * 16 + q * 4 + r) * FDIM + f] =
                            f2bf(acc[it][ft][r] + o[r]);
                }
        }
    }

    gbar(ep0 + 3);

    // ============ Phase O: out = relu(sum_k part_k) / S ========================
    {
        const size_t idx = ((size_t)b * 512 + t) * 8;
        const float inv = 1.0f / (*Sg);
        float s[8] = {};
        #pragma unroll
        for (int k = 0; k < 4; ++k) {
            const s8v v = *(const s8v*)(part + (size_t)k * NN * FDIM + idx);
            #pragma unroll
            for (int j = 0; j < 8; ++j) {
                union { uint32_t u; float f; } cv;
                cv.u = ((uint32_t)(uint16_t)v[j]) << 16;
                s[j] += cv.f;
            }
        }
        fx4 r0, r1;
        #pragma unroll
        for (int j = 0; j < 4; ++j) {
            r0[j] = fmaxf(s[j], 0.f) * inv;
            r1[j] = fmaxf(s[4 + j], 0.f) * inv;
        }
        *(fx4*)(out + idx) = r0;
        *(fx4*)(out + idx + 4) = r1;
    }
}

extern "C" void kernel_launch(void* const* d_in, const int* in_sizes, int n_in,
                              void* d_out, int out_size, void* d_ws, size_t ws_size,
                              hipStream_t stream) {
    const float* x     = (const float*)d_in[0];
    const int*   adj   = (const int*)d_in[1];
    const float* W     = (const float*)d_in[2];
    const float* bias  = (const float*)d_in[3];
    const float* att_w = (const float*)d_in[4];
    // att_b (d_in[5]) cancels exactly in the softmax — unused.
    float* out = (float*)d_out;
    char* ws = (char*)d_ws;
    uint16_t* gt   = (uint16_t*)(ws + 0);            // 2 MB: bf16(h) transposed
    float*    a1p  = (float*)(ws + 2097152);         // 64 KB
    float*    a2p  = (float*)(ws + 2162688);         // 64 KB
    float*    E1   = (float*)(ws + 2228224);         // 16 KB
    float*    E2   = (float*)(ws + 2244608);         // 16 KB
    float*    wraw = (float*)(ws + 2260992);         // 16 KB
    float*    Sg   = (float*)(ws + 2277376);         // 256 B
    uint16_t* part = (uint16_t*)(ws + 2277632);      // 4 x 2 MB bf16 split-K partials
    (void)in_sizes; (void)n_in; (void)out_size; (void)ws_size;

    gat_all<<<dim3(NBLK), 512, 0, stream>>>(x, adj, W, bias, att_w, gt, a1p, a2p,
                                            E1, E2, wraw, Sg, part, out);
}

// Round 3
// 148.105 us; speedup vs baseline: 1.9384x; 1.2991x over previous
//
#include <hip/hip_runtime.h>
#include <cstdint>
#include <cstddef>

#define NN 4096
#define FDIM 256

typedef __attribute__((ext_vector_type(4))) float fx4;
typedef __attribute__((ext_vector_type(8))) short s8v;

__device__ inline uint16_t f2bf(float f) {
    union { float f; uint32_t u; } v; v.f = f;
    const uint32_t u = v.u;
    return (uint16_t)((u + 0x7FFFu + ((u >> 16) & 1u)) >> 16);
}

// ---------------- k_h: h = x @ W.T + b (kept in regs/LDS only) ----------------
// Outputs: gt = bf16(h) transposed [f][j] cb-swizzled (MFMA B-operand layout),
// a1p/a2p = per-f-chunk partials of h@att_w1 / h@att_w2. h never hits HBM.
// 64x64 tile, 512 thr, dbuf + reg prefetch, intra-block K-split. 69.6KB -> 2/CU.
__global__ __launch_bounds__(512, 4) void k_h(const float* __restrict__ x,
        const float* __restrict__ W, const float* __restrict__ bias,
        const float* __restrict__ att_w, uint16_t* __restrict__ gt,
        float* __restrict__ a1p, float* __restrict__ a2p) {
    __shared__ __align__(16) float xs[2][64 * 68];
    __shared__ __align__(16) float wt[2][64 * 68];
    const int bi = blockIdx.x, bf = blockIdx.y;
    const int t = threadIdx.x;
    const int t256 = t & 255;
    const int kh = t >> 8;                         // K-half: 0 or 1
    const int tx = t256 & 15, ty = t256 >> 4;      // f-group, i-group
    float acc[4][4] = {};
    float rx[8], rw[8];
    #pragma unroll
    for (int u = 0; u < 8; ++u) {
        const int e = t + 512 * u, r = e >> 6, c = e & 63;
        rx[u] = x[(size_t)(bi * 64 + r) * 256 + c];
        rw[u] = W[(size_t)(bf * 64 + r) * 256 + c];
    }
    for (int p = 0; p < 4; ++p) {
        float* xb = xs[p & 1];
        float* wb = wt[p & 1];
        #pragma unroll
        for (int u = 0; u < 8; ++u) {
            const int e = t + 512 * u, r = e >> 6, c = e & 63;
            const int sw = 8 * ((c & 7) ^ ((c >> 3) & 7));
            xb[c * 68 + (r ^ sw)] = rx[u];
            wb[c * 68 + (r ^ sw)] = rw[u];
        }
        __syncthreads();
        if (p < 3) {
            const int kc = (p + 1) * 64;
            #pragma unroll
            for (int u = 0; u < 8; ++u) {
                const int e = t + 512 * u, r = e >> 6, c = e & 63;
                rx[u] = x[(size_t)(bi * 64 + r) * 256 + kc + c];
                rw[u] = W[(size_t)(bf * 64 + r) * 256 + kc + c];
            }
        }
        #pragma unroll 8
        for (int k = 0; k < 32; ++k) {
            const int kk = kh * 32 + k;
            const int sw = 8 * ((kk & 7) ^ ((kk >> 3) & 7));
            const fx4 av = *(const fx4*)(xb + kk * 68 + ((ty * 4) ^ sw));
            const fx4 bv = *(const fx4*)(wb + kk * 68 + ((tx * 4) ^ sw));
            #pragma unroll
            for (int u = 0; u < 4; ++u)
                #pragma unroll
                for (int v = 0; v < 4; ++v)
                    acc[u][v] += av[u] * bv[v];
        }
    }
    __syncthreads();
    float* cbuf = xs[0];
    if (kh == 1) {
        #pragma unroll
        for (int u = 0; u < 4; ++u)
            *(fx4*)(cbuf + t256 * 16 + u * 4) = *(const fx4*)(&acc[u][0]);
    }
    __syncthreads();
    if (kh == 0) {
        float* tileT = wt[0];     // dead after compute: [f_local][j_local] pad 68
        #pragma unroll
        for (int u = 0; u < 4; ++u) {
            const fx4 o = *(const fx4*)(cbuf + t256 * 16 + u * 4);
            #pragma unroll
            for (int v = 0; v < 4; ++v) acc[u][v] += o[v];
        }
        const fx4 bv = *(const fx4*)(bias + bf * 64 + tx * 4);
        const fx4 w1v = *(const fx4*)(att_w + bf * 64 + tx * 4);
        const fx4 w2v = *(const fx4*)(att_w + 256 + bf * 64 + tx * 4);
        #pragma unroll
        for (int u = 0; u < 4; ++u) {
            const int i = bi * 64 + ty * 4 + u;
            fx4 r;
            float s1 = 0.f, s2 = 0.f;
            #pragma unroll
            for (int v = 0; v < 4; ++v) {
                r[v] = acc[u][v] + bv[v];
                s1 += r[v] * w1v[v];
                s2 += r[v] * w2v[v];
            }
            #pragma unroll
            for (int v = 0; v < 4; ++v)
                tileT[(tx * 4 + v) * 68 + ty * 4 + u] = r[v];
            #pragma unroll
            for (int d = 8; d > 0; d >>= 1) {
                s1 += __shfl_down(s1, d, 16);
                s2 += __shfl_down(s2, d, 16);
            }
            if (tx == 0) {
                a1p[bf * NN + i] = s1;
                a2p[bf * NN + i] = s2;
            }
        }
    }
    __syncthreads();
    {   // gt store: all 512 threads, 64 f-rows x 8 cb-groups of 8
        const float* tileT = wt[0];
        const int fl = t >> 3, cb = t & 7;
        const int pcb = cb ^ (fl & 7);
        s8v v;
        #pragma unroll
        for (int lo = 0; lo < 8; ++lo)
            v[lo] = (short)f2bf(tileT[fl * 68 + cb * 8 + lo]);
        *(s8v*)(gt + (size_t)(bf * 64 + fl) * NN + bi * 64 + pcb * 8) = v;
    }
}

// ---- k_prep: reduce a-partials, max/exp -> E1,E2, Sg=0, first-4096-edge scan ----
__global__ __launch_bounds__(1024) void k_prep(const float* __restrict__ a1p,
        const float* __restrict__ a2p, const int* __restrict__ adj,
        float* __restrict__ E1, float* __restrict__ E2,
        float* __restrict__ wraw, float* __restrict__ Sg) {
    __shared__ float E1s[NN];
    __shared__ float E2s[NN];
    __shared__ float red1[16], red2[16];
    __shared__ int wtot[16];
    __shared__ int base_s;
    const int t = threadIdx.x, lane = t & 63, wv = t >> 6;
    fx4 v1 = {0.f, 0.f, 0.f, 0.f}, v2 = {0.f, 0.f, 0.f, 0.f};
    #pragma unroll
    for (int bf = 0; bf < 4; ++bf) {
        v1 += *(const fx4*)(a1p + bf * NN + t * 4);
        v2 += *(const fx4*)(a2p + bf * NN + t * 4);
    }
    float m1 = fmaxf(fmaxf(v1[0], v1[1]), fmaxf(v1[2], v1[3]));
    float m2 = fmaxf(fmaxf(v2[0], v2[1]), fmaxf(v2[2], v2[3]));
    #pragma unroll
    for (int d = 32; d > 0; d >>= 1) {
        m1 = fmaxf(m1, __shfl_down(m1, d));
        m2 = fmaxf(m2, __shfl_down(m2, d));
    }
    if (lane == 0) { red1[wv] = m1; red2[wv] = m2; }
    __syncthreads();
    if (t == 0) {
        float mm1 = -1e30f, mm2 = -1e30f;
        for (int k = 0; k < 16; ++k) {
            mm1 = fmaxf(mm1, red1[k]);
            mm2 = fmaxf(mm2, red2[k]);
        }
        red1[0] = mm1; red2[0] = mm2;
        *Sg = 0.f;
        base_s = 0;
    }
    __syncthreads();
    const float M1 = red1[0], M2 = red2[0];
    fx4 e1v, e2v, z4 = {0.f, 0.f, 0.f, 0.f};
    #pragma unroll
    for (int j = 0; j < 4; ++j) {
        e1v[j] = expf(v1[j] - M1);
        e2v[j] = expf(v2[j] - M2);
    }
    *(fx4*)(E1s + t * 4) = e1v;
    *(fx4*)(E2s + t * 4) = e2v;
    *(fx4*)(E1 + t * 4) = e1v;
    *(fx4*)(E2 + t * 4) = e2v;
    *(fx4*)(wraw + t * 4) = z4;
    __syncthreads();
    for (int row = 0; row < NN; ++row) {
        const int base = base_s;           // uniform
        if (base >= NN) break;             // uniform break
        const int4 a = ((const int4*)(adj + (size_t)row * NN))[t];
        const int vj[4] = {a.x, a.y, a.z, a.w};
        int cnt = 0;
        #pragma unroll
        for (int j = 0; j < 4; ++j) cnt += (vj[j] == 1);
        int inc = cnt;
        #pragma unroll
        for (int d = 1; d < 64; d <<= 1) {
            const int y = __shfl_up(inc, d);
            if (lane >= d) inc += y;
        }
        if (lane == 63) wtot[wv] = inc;
        __syncthreads();                   // B1
        int wbase = 0, total = 0;
        #pragma unroll
        for (int w = 0; w < 16; ++w) {
            const int xw = wtot[w];
            total += xw;
            wbase += (w < wv) ? xw : 0;
        }
        if (t == 0) base_s = base + total;
        int r = base + wbase + inc - cnt;
        if (cnt && r < NN) {
            const float e1 = E1s[row];
            #pragma unroll
            for (int j = 0; j < 4; ++j) {
                if (vj[j] == 1) {
                    if (r < NN) wraw[r] = e1 * E2s[t * 4 + j];
                    ++r;
                }
            }
        }
        __syncthreads();                   // B2
    }
}

// -------- k_fused: part = (adj * bf16(wraw)) @ gt^T (bf16 MFMA, split-K) + S ----
// wraw folded into the A-operand (k_g kernel eliminated). S exact via VALU from
// the adj regs already in flight. LDS 42KB -> 3 blocks/CU; adj+wraw prefetched
// one step ahead so their HBM latency hides under the MFMA phase.
__global__ __launch_bounds__(256, 3) void k_fused(const int* __restrict__ adj,
        const uint16_t* __restrict__ gt, const float* __restrict__ E1,
        const float* __restrict__ E2, const float* __restrict__ wraw,
        uint16_t* __restrict__ part, float* __restrict__ Sg, int krange) {
    __shared__ __align__(16) uint16_t As[64 * 72];     // padded (explicit writes)
    __shared__ __align__(16) uint16_t Gs[256 * 64];    // linear (DMA target)
    __shared__ float sgred[4];
    const int ib = blockIdx.x, ks = blockIdx.y;
    const int t = threadIdx.x;
    const int wv = t >> 6, lane = t & 63;
    const int q = lane >> 4, m16 = lane & 15;
    const int i0 = ib * 64, k0 = ks * krange;
    const int ksteps = krange >> 6;
    const int ar = t >> 4, ac4 = (t & 15) * 4;         // adj/As staging mapping
    const int fr = lane >> 3, cb = lane & 7;           // Gs DMA lane mapping
    fx4 acc[4][4];
    #pragma unroll
    for (int a = 0; a < 4; ++a)
        #pragma unroll
        for (int b2 = 0; b2 < 4; ++b2) acc[a][b2] = (fx4){0.f, 0.f, 0.f, 0.f};
    float sS = 0.f;
    float e1r[4];
    #pragma unroll
    for (int p = 0; p < 4; ++p) e1r[p] = E1[i0 + p * 16 + ar];
    int4 ra[4];
    #pragma unroll
    for (int p = 0; p < 4; ++p)
        ra[p] = *(const int4*)(adj + (size_t)(i0 + p * 16 + ar) * NN + k0 + ac4);
    fx4 rw4 = *(const fx4*)(wraw + k0 + ac4);
    fx4 re2 = *(const fx4*)(E2 + k0 + ac4);

    for (int stp = 0; stp < ksteps; ++stp) {
        const int kk = k0 + stp * 64;
        // ---- As: adj gate x bf16(wraw) + exact S partial (VALU) ----
        const uint16_t wb0 = f2bf(rw4[0]), wb1 = f2bf(rw4[1]);
        const uint16_t wb2 = f2bf(rw4[2]), wb3 = f2bf(rw4[3]);
        #pragma unroll
        for (int p = 0; p < 4; ++p) {
            uint2 wo;
            wo.x = (ra[p].x == 1 ? (uint32_t)wb0 : 0u) |
                   ((ra[p].y == 1 ? (uint32_t)wb1 : 0u) << 16);
            wo.y = (ra[p].z == 1 ? (uint32_t)wb2 : 0u) |
                   ((ra[p].w == 1 ? (uint32_t)wb3 : 0u) << 16);
            *(uint2*)(&As[(p * 16 + ar) * 72 + ac4]) = wo;
            sS += e1r[p] * ((ra[p].x == 1 ? re2[0] : 0.f) +
                            (ra[p].y == 1 ? re2[1] : 0.f) +
                            (ra[p].z == 1 ? re2[2] : 0.f) +
                            (ra[p].w == 1 ? re2[3] : 0.f));
        }
        // ---- Gs: DMA 1 KB (8 f-rows) per instr, 8 instrs/wave ----
        #pragma unroll
        for (int p = 0; p < 8; ++p) {
            const int f0 = wv * 64 + p * 8;
            const uint16_t* gp = gt + (size_t)(f0 + fr) * NN + kk + cb * 8;
            __builtin_amdgcn_global_load_lds(
                (const __attribute__((address_space(1))) uint32_t*)gp,
                (__attribute__((address_space(3))) uint32_t*)(Gs + f0 * 64),
                16, 0, 0);
        }
        __syncthreads();   // drains DMA (vmcnt0) + As LDS writes
        // ---- prefetch next step's adj/wraw/E2 (drains next barrier) ----
        if (stp + 1 < ksteps) {
            #pragma unroll
            for (int p = 0; p < 4; ++p)
                ra[p] = *(const int4*)(adj + (size_t)(i0 + p * 16 + ar) * NN +
                                       kk + 64 + ac4);
            rw4 = *(const fx4*)(wraw + kk + 64 + ac4);
            re2 = *(const fx4*)(E2 + kk + 64 + ac4);
        }
        s8v afr[4][2];
        #pragma unroll
        for (int it = 0; it < 4; ++it)
            #pragma unroll
            for (int khh = 0; khh < 2; ++khh)
                afr[it][khh] = *(const s8v*)(As + (it * 16 + m16) * 72 + khh * 32 + q * 8);
        #pragma unroll
        for (int ft = 0; ft < 4; ++ft) {
            #pragma unroll
            for (int khh = 0; khh < 2; ++khh) {
                const int row = wv * 64 + ft * 16 + m16;
                const int pcb = ((khh << 2) | q) ^ (m16 & 7);   // un-swizzle
                const s8v bfr = *(const s8v*)(Gs + row * 64 + pcb * 8);
                #pragma unroll
                for (int it = 0; it < 4; ++it)
                    acc[it][ft] = __builtin_amdgcn_mfma_f32_16x16x32_bf16(
                        afr[it][khh], bfr, acc[it][ft], 0, 0, 0);
            }
        }
        __syncthreads();   // As/Gs reusable
    }
    #pragma unroll
    for (int d = 32; d > 0; d >>= 1) sS += __shfl_down(sS, d);
    if (lane == 0) sgred[wv] = sS;
    __syncthreads();
    if (t == 0)
        atomicAdd(Sg, sgred[0] + sgred[1] + sgred[2] + sgred[3]);
    // bf16 partials; C/D layout: col=lane&15, row=(lane>>4)*4+reg
    uint16_t* dst = part + (size_t)ks * NN * FDIM;
    #pragma unroll
    for (int it = 0; it < 4; ++it) {
        #pragma unroll
        for (int ft = 0; ft < 4; ++ft) {
            const int f = wv * 64 + ft * 16 + m16;
            #pragma unroll
            for (int r = 0; r < 4; ++r) {
                const int i = i0 + it * 16 + q * 4 + r;
                dst[(size_t)i * FDIM + f] = f2bf(acc[it][ft][r]);
            }
        }
    }
}

// -------- k_out: out = relu(sum_k part_k) / S (bf16 partials, 8 f/thread) --------
__global__ __launch_bounds__(256) void k_out(const uint16_t* __restrict__ part,
        const float* __restrict__ Sg, float* __restrict__ out, int nsplit) {
    const size_t idx = ((size_t)blockIdx.x * 256 + threadIdx.x) * 8;
    const float inv = 1.0f / (*Sg);
    float s[8] = {};
    for (int k = 0; k < nsplit; ++k) {
        const s8v v = *(const s8v*)(part + (size_t)k * NN * FDIM + idx);
        #pragma unroll
        for (int j = 0; j < 8; ++j) {
            union { uint32_t u; float f; } cv;
            cv.u = ((uint32_t)(uint16_t)v[j]) << 16;
            s[j] += cv.f;
        }
    }
    fx4 r0, r1;
    #pragma unroll
    for (int j = 0; j < 4; ++j) {
        r0[j] = fmaxf(s[j], 0.f) * inv;
        r1[j] = fmaxf(s[4 + j], 0.f) * inv;
    }
    *(fx4*)(out + idx) = r0;
    *(fx4*)(out + idx + 4) = r1;
}

extern "C" void kernel_launch(void* const* d_in, const int* in_sizes, int n_in,
                              void* d_out, int out_size, void* d_ws, size_t ws_size,
                              hipStream_t stream) {
    const float* x     = (const float*)d_in[0];
    const int*   adj   = (const int*)d_in[1];
    const float* W     = (const float*)d_in[2];
    const float* bias  = (const float*)d_in[3];
    const float* att_w = (const float*)d_in[4];
    // att_b (d_in[5]) cancels exactly in the softmax — unused.
    float* out = (float*)d_out;
    char* ws = (char*)d_ws;
    uint16_t* gt   = (uint16_t*)(ws + 0);            // 2 MB: bf16(h) transposed
    float*    a1p  = (float*)(ws + 2097152);         // 64 KB (4 x 4096)
    float*    a2p  = (float*)(ws + 2162688);         // 64 KB
    float*    E1   = (float*)(ws + 2228224);         // 16 KB
    float*    E2   = (float*)(ws + 2244608);         // 16 KB
    float*    wraw = (float*)(ws + 2260992);         // 16 KB
    float*    Sg   = (float*)(ws + 2277376);         // 256 B
    uint16_t* part = (uint16_t*)(ws + 2277632);      // splitk x 2 MB (bf16)
    (void)in_sizes; (void)n_in; (void)out_size;

    const size_t avail = (ws_size > 2277632) ? (ws_size - 2277632) : 0;
    int splitk = 1;
    while (splitk < 8 &&
           (size_t)(splitk * 2) * NN * FDIM * sizeof(uint16_t) <= avail)
        splitk <<= 1;
    const int krange = NN / splitk;

    k_h    <<<dim3(64, 4), 512, 0, stream>>>(x, W, bias, att_w, gt, a1p, a2p);
    k_prep <<<dim3(1), 1024, 0, stream>>>(a1p, a2p, adj, E1, E2, wraw, Sg);
    k_fused<<<dim3(64, splitk), 256, 0, stream>>>(adj, gt, E1, E2, wraw, part, Sg, krange);
    k_out  <<<dim3(512), 256, 0, stream>>>(part, Sg, out, splitk);
}